// Round 3
// baseline (278.143 us; speedup 1.0000x reference)
//
#include <hip/hip_runtime.h>
#include <stdint.h>

typedef __attribute__((ext_vector_type(8))) short short8;
typedef __attribute__((ext_vector_type(4))) float f32x4;
typedef __attribute__((ext_vector_type(16))) float f32x16;
typedef __attribute__((ext_vector_type(4))) float float4v;
typedef __attribute__((ext_vector_type(4))) unsigned short ushort4v;
typedef __attribute__((ext_vector_type(2))) unsigned int uint2v;
typedef __attribute__((ext_vector_type(4))) unsigned int uint4v;

#define MFMA16(a,b,c) __builtin_amdgcn_mfma_f32_16x16x32_bf16((a),(b),(c),0,0,0)
#define MFMA32(a,b,c) __builtin_amdgcn_mfma_f32_32x32x16_bf16((a),(b),(c),0,0,0)

typedef const __attribute__((address_space(1))) void gld_src_t;
typedef __attribute__((address_space(3))) void gld_dst_t;
#define GLOAD_LDS16(g, l) __builtin_amdgcn_global_load_lds((gld_src_t*)(g), (gld_dst_t*)(l), 16, 0, 0)

__device__ __forceinline__ unsigned short f2bf(float f) {
  union { float f; unsigned int u; } v; v.f = f;
  unsigned int u = v.u;
  unsigned int r = (u + 0x7fffu + ((u >> 16) & 1u)) >> 16;  // RNE
  return (unsigned short)r;
}

// hardware packed f32x2 -> bf16x2 (RNE), low = a, high = b
__device__ __forceinline__ unsigned cvtpk(float a, float b) {
  unsigned r;
  asm("v_cvt_pk_bf16_f32 %0, %1, %2" : "=v"(r) : "v"(a), "v"(b));
  return r;
}

// ---------------- convert fp32 -> bf16, vectorized ----------------
__global__ __launch_bounds__(256) void cvt_f32_bf16(const float* __restrict__ in,
                                                    unsigned short* __restrict__ out) {
  int i = blockIdx.x * 256 + threadIdx.x;
  float4v v = ((const float4v*)in)[i];
  ushort4v o;
  o[0] = f2bf(v[0]); o[1] = f2bf(v[1]); o[2] = f2bf(v[2]); o[3] = f2bf(v[3]);
  ((ushort4v*)out)[i] = o;
}

// ------------- transpose+convert W [K][N] f32 -> WT [N][K] bf16 -------------
__global__ __launch_bounds__(256) void cvt_transpose(const float* __restrict__ W,
                                                     unsigned short* __restrict__ WT,
                                                     int K, int N) {
  __shared__ unsigned short lds[64][72];
  int k0 = blockIdx.x * 64, n0 = blockIdx.y * 64;
  int t = threadIdx.x, tr = t >> 4, tc = t & 15;
#pragma unroll
  for (int p = 0; p < 4; ++p) {
    int k = tr + p * 16;
    float4v v = *(const float4v*)&W[(size_t)(k0 + k) * N + n0 + tc * 4];
    lds[tc * 4 + 0][k] = f2bf(v[0]);
    lds[tc * 4 + 1][k] = f2bf(v[1]);
    lds[tc * 4 + 2][k] = f2bf(v[2]);
    lds[tc * 4 + 3][k] = f2bf(v[3]);
  }
  __syncthreads();
#pragma unroll
  for (int p = 0; p < 4; ++p) {
    int n = tr + p * 16;
    ushort4v o;
    o[0] = lds[n][tc * 4 + 0]; o[1] = lds[n][tc * 4 + 1];
    o[2] = lds[n][tc * 4 + 2]; o[3] = lds[n][tc * 4 + 3];
    *(ushort4v*)&WT[(size_t)(n0 + n) * K + k0 + tc * 4] = o;
  }
}

// ------------- transpose V [bh][s][64] -> Vt [bh][64][s] (bf16) -------------
__global__ __launch_bounds__(256) void transpose_v(const unsigned short* __restrict__ V,
                                                   unsigned short* __restrict__ Vt) {
  __shared__ unsigned short lds[64][72];
  int bh = blockIdx.x, s0 = blockIdx.y * 64;
  int t = threadIdx.x, tr = t >> 4, tc = t & 15;
  const unsigned short* Vb = V + (size_t)bh * 2048 * 64;
  unsigned short* Vtb = Vt + (size_t)bh * 64 * 2048;
#pragma unroll
  for (int p = 0; p < 4; ++p) {
    int s = tr + p * 16;
    ushort4v v = *(const ushort4v*)&Vb[(size_t)(s0 + s) * 64 + tc * 4];
    lds[tc * 4 + 0][s] = v[0];
    lds[tc * 4 + 1][s] = v[1];
    lds[tc * 4 + 2][s] = v[2];
    lds[tc * 4 + 3][s] = v[3];
  }
  __syncthreads();
#pragma unroll
  for (int p = 0; p < 4; ++p) {
    int d = tr + p * 16;
    ushort4v o;
    o[0] = lds[d][tc * 4 + 0]; o[1] = lds[d][tc * 4 + 1];
    o[2] = lds[d][tc * 4 + 2]; o[3] = lds[d][tc * 4 + 3];
    *(ushort4v*)&Vtb[(size_t)d * 2048 + s0 + tc * 4] = o;
  }
}

// ---------------- shared 128x128 bf16 GEMM mainloop (m97 structure) ----------------
__device__ __forceinline__ void gemm_mainloop_128(const unsigned short* __restrict__ A,
                                                  const unsigned short* __restrict__ BT,
                                                  int K, int row0, int col0,
                                                  unsigned short* Als, unsigned short* Bls,
                                                  f32x4 acc[4][4]) {
  int t = threadIdx.x;
  int w = t >> 6, l = t & 63;
  int lo = l & 15, hi = l >> 4;
  int wr = w >> 1, wc = w & 1;
  const unsigned short* Ag1 = A + (size_t)(row0 + (t >> 2)) * K + (t & 3) * 8;
  const unsigned short* Ag2 = A + (size_t)(row0 + 64 + (t >> 2)) * K + (t & 3) * 8;
  const unsigned short* Bg1 = BT + (size_t)(col0 + (t >> 2)) * K + (t & 3) * 8;
  const unsigned short* Bg2 = BT + (size_t)(col0 + 64 + (t >> 2)) * K + (t & 3) * 8;
  unsigned short* Ald1 = Als + w * 512;
  unsigned short* Ald2 = Als + 2048 + w * 512;
  unsigned short* Bld1 = Bls + w * 512;
  unsigned short* Bld2 = Bls + 2048 + w * 512;
  int aoff[4], boff[4];
#pragma unroll
  for (int m = 0; m < 4; ++m) aoff[m] = (wr * 64 + m * 16 + lo) * 32 + hi * 8;
#pragma unroll
  for (int n = 0; n < 4; ++n) boff[n] = (wc * 64 + n * 16 + lo) * 32 + hi * 8;

  for (int k0 = 0; k0 < K; k0 += 32) {
    GLOAD_LDS16(Ag1 + k0, Ald1);
    GLOAD_LDS16(Ag2 + k0, Ald2);
    GLOAD_LDS16(Bg1 + k0, Bld1);
    GLOAD_LDS16(Bg2 + k0, Bld2);
    __syncthreads();
    short8 af[4], bf[4];
#pragma unroll
    for (int m = 0; m < 4; ++m) af[m] = *(const short8*)&Als[aoff[m]];
#pragma unroll
    for (int n = 0; n < 4; ++n) bf[n] = *(const short8*)&Bls[boff[n]];
#pragma unroll
    for (int m = 0; m < 4; ++m)
#pragma unroll
      for (int n = 0; n < 4; ++n)
        acc[m][n] = MFMA16(af[m], bf[n], acc[m][n]);
    __syncthreads();
  }
}

// -------- GEMM1: xb @ W_qkvT + b -> scatter Q(*0.125*log2e)/K/V [bh][s][64] --------
__global__ __launch_bounds__(256) void gemm_qkv(const unsigned short* __restrict__ xb,
                                                const unsigned short* __restrict__ WT,
                                                const float* __restrict__ bias,
                                                unsigned short* __restrict__ Q,
                                                unsigned short* __restrict__ Ko,
                                                unsigned short* __restrict__ V) {
  __shared__ unsigned short Als[4096], Bls[4096];
  f32x4 zero = {0.f, 0.f, 0.f, 0.f};
  f32x4 acc[4][4];
#pragma unroll
  for (int m = 0; m < 4; ++m)
#pragma unroll
    for (int n = 0; n < 4; ++n) acc[m][n] = zero;
  int row0 = blockIdx.x * 128, col0 = blockIdx.y * 128;
  gemm_mainloop_128(xb, WT, 1024, row0, col0, Als, Bls, acc);

  int t = threadIdx.x, w = t >> 6, l = t & 63, lo = l & 15, hi = l >> 4;
  int wr = w >> 1, wc = w & 1;
#pragma unroll
  for (int m = 0; m < 4; ++m) {
#pragma unroll
    for (int n = 0; n < 4; ++n) {
      int col = col0 + wc * 64 + n * 16 + lo;
      float b = bias[col];
      int which = col >> 10, hd = col & 1023, h = hd >> 6, d = hd & 63;
#pragma unroll
      for (int r = 0; r < 4; ++r) {
        int row = row0 + wr * 64 + m * 16 + hi * 4 + r;
        int bb = row >> 11, s = row & 2047;
        float v = acc[m][n][r] + b;
        size_t dst = ((size_t)(bb * 16 + h) * 2048 + s) * 64 + d;
        if (which == 0)      Q[dst]  = f2bf(v * 0.18033688011112042f);  // 0.125*log2(e)
        else if (which == 1) Ko[dst] = f2bf(v);
        else                 V[dst]  = f2bf(v);
      }
    }
  }
}

// ---------------- GEMM2: attn @ W_outT + b_out -> fp32 out ----------------
__global__ __launch_bounds__(256) void gemm_out(const unsigned short* __restrict__ attn,
                                                const unsigned short* __restrict__ WT,
                                                const float* __restrict__ bias,
                                                float* __restrict__ out) {
  __shared__ unsigned short Als[4096], Bls[4096];
  f32x4 zero = {0.f, 0.f, 0.f, 0.f};
  f32x4 acc[4][4];
#pragma unroll
  for (int m = 0; m < 4; ++m)
#pragma unroll
    for (int n = 0; n < 4; ++n) acc[m][n] = zero;
  int row0 = blockIdx.x * 128, col0 = blockIdx.y * 128;
  gemm_mainloop_128(attn, WT, 1024, row0, col0, Als, Bls, acc);

  int t = threadIdx.x, w = t >> 6, l = t & 63, lo = l & 15, hi = l >> 4;
  int wr = w >> 1, wc = w & 1;
#pragma unroll
  for (int m = 0; m < 4; ++m) {
#pragma unroll
    for (int n = 0; n < 4; ++n) {
      int col = col0 + wc * 64 + n * 16 + lo;
      float b = bias[col];
#pragma unroll
      for (int r = 0; r < 4; ++r) {
        int row = row0 + wr * 64 + m * 16 + hi * 4 + r;
        out[(size_t)row * 1024 + col] = acc[m][n][r] + b;
      }
    }
  }
}

// ============ flash attention v5: LDS-staged K/V, fixed swizzle, 4 blocks/CU ========
// v4 post-mortem: SQ_LDS_BANK_CONFLICT = 2^23 exactly = 4 extra cyc per ds_read_b128.
// Root cause: row stride (128B) == bank period, and the old chunk^=(row&7) swizzle
// leaves lanes {lo, lo+8, lo+16, lo+24} (equal lo&7) on the SAME 16B slot -> 4-way
// group conflict. Fix: slot = chunk ^ (row&7) ^ (row>>3) -- any 8 consecutive lanes
// AND the mod-8 lane quads now hit 8 distinct slots (full 32-bank coverage).
// Second fix: __launch_bounds__(256,4) -> all 4 blocks/CU resident (grid is exactly
// 4/CU; 4x32KB=128KB LDS). v4's 2-wave/SIMD pool couldn't cover the per-iter serial
// chain (wall was ~2x the throughput bound); 4 waves/SIMD converts stall to issue.
__global__ __launch_bounds__(256, 4) void attn_fwd2(const unsigned short* __restrict__ Q,
                                                    const unsigned short* __restrict__ Kg,
                                                    const unsigned short* __restrict__ Vt,
                                                    unsigned short* __restrict__ attn_out) {
  const int S = 2048;
  __shared__ unsigned short Kls[2][4096];   // [buf][64 rows][8 slots x 16B] swizzled
  __shared__ unsigned short Vls[2][4096];   // [buf][64 d   ][8 slots x 16B] swizzled

  int bid = blockIdx.x;
  int swz = (bid & 7) * 128 + (bid >> 3);   // 8 bh per XCD -> K+Vt fit 4MB L2
  int bh = swz >> 4, qt = swz & 15;
  int t = threadIdx.x, w = t >> 6, l = t & 63;
  int lo = l & 31, hi = l >> 5;
  int qi = qt * 128 + w * 32 + lo;
  const unsigned short* Qr = Q + ((size_t)bh * S + qi) * 64 + hi * 8;
  const char* KbB = (const char*)(Kg + (size_t)bh * S * 64);
  const char* VbB = (const char*)(Vt + (size_t)bh * 64 * S);

  short8 qf[4];
#pragma unroll
  for (int ks = 0; ks < 4; ++ks) qf[ks] = *(const short8*)(Qr + ks * 16);

  // ---- staging geometry: 16 gload_lds per block-iter (4/wave), 1KB each ----
  // instr j (j=0..7 per tensor) covers tile rows 8j..8j+7; lane l writes LDS byte
  // j*1024 + l*16 = (row 8j+(l>>3), slot l&7). Stored layout: slot = g ^ s(row),
  // s(row) = (row&7)^(row>>3). => source global chunk g = (l&7) ^ (l>>3) ^ j.
  int lrow = l >> 3;                                     // 0..7 (row&7 within instr)
  int j0 = w * 2;                                        // this wave's 2 K + 2 V instrs
  int g0B = (((l & 7) ^ lrow ^ j0) << 4);                // source chunk bytes, instr j0
  int g1B = (((l & 7) ^ lrow ^ (j0 + 1)) << 4);          // source chunk bytes, instr j0+1
  size_t kg0 = (size_t)(8 * j0 + lrow) * 128 + g0B;      // + kv0*128
  size_t kg1 = (size_t)(8 * j0 + 8 + lrow) * 128 + g1B;
  size_t vg0 = (size_t)(8 * j0 + lrow) * 4096 + g0B;     // + kv0*2
  size_t vg1 = (size_t)(8 * j0 + 8 + lrow) * 4096 + g1B;

  // ---- fragment read offsets (ushort idx), loop-invariant ----
  // want global (row, chunk=2ks+hi) -> LDS[row][(2ks+hi) ^ s(row)]
  // koff0: row = lo (s = (lo&7)^(lo>>3));  koff1: row = lo+32 (s ^= 4)
  int koff0[4], koff1[4];
#pragma unroll
  for (int ks = 0; ks < 4; ++ks) {
    int srow = (lo & 7) ^ (lo >> 3);
    koff0[ks] = lo * 64 + (((2 * ks + hi) ^ srow) << 3);
    koff1[ks] = (lo + 32) * 64 + (((2 * ks + hi) ^ srow ^ 4) << 3);
  }

  // ---- prologue: stage tile 0 into buffer 0 ----
  GLOAD_LDS16(KbB + kg0, &Kls[0][j0 * 512]);
  GLOAD_LDS16(KbB + kg1, &Kls[0][(j0 + 1) * 512]);
  GLOAD_LDS16(VbB + vg0, &Vls[0][j0 * 512]);
  GLOAD_LDS16(VbB + vg1, &Vls[0][(j0 + 1) * 512]);

  const f32x16 zf = {0.f,0.f,0.f,0.f,0.f,0.f,0.f,0.f,0.f,0.f,0.f,0.f,0.f,0.f,0.f,0.f};
  f32x16 ot0 = zf, ot1 = zf;
  float m = -1e30f, lsum = 0.f;   // lsum is PER-HALF; combined in epilogue

  __syncthreads();                // tile 0 ready (vmcnt(0) + barrier)

  for (int it = 0; it < 32; ++it) {
    int cur = it & 1, nxt = cur ^ 1;
    size_t kvn = (size_t)(((it + 1) & 31) * 64);  // wrap on last iter: harmless re-stage
    // ---- issue next-tile staging; drained by syncthreads at iter end ----
    GLOAD_LDS16(KbB + kvn * 128 + kg0, &Kls[nxt][j0 * 512]);
    GLOAD_LDS16(KbB + kvn * 128 + kg1, &Kls[nxt][(j0 + 1) * 512]);
    GLOAD_LDS16(VbB + kvn * 2 + vg0, &Vls[nxt][j0 * 512]);
    GLOAD_LDS16(VbB + kvn * 2 + vg1, &Vls[nxt][(j0 + 1) * 512]);

    // ---- K fragments from LDS (conflict-free swizzled b128 reads) ----
    short8 kf0[4], kf1[4];
#pragma unroll
    for (int ks = 0; ks < 4; ++ks) {
      kf0[ks] = *(const short8*)&Kls[cur][koff0[ks]];
      kf1[ks] = *(const short8*)&Kls[cur][koff1[ks]];
    }
    f32x16 st0 = zf, st1 = zf;
    __builtin_amdgcn_s_setprio(1);
#pragma unroll
    for (int ks = 0; ks < 4; ++ks) {
      st0 = MFMA32(kf0[ks], qf[ks], st0);
      st1 = MFMA32(kf1[ks], qf[ks], st1);
    }
    __builtin_amdgcn_s_setprio(0);
    // ---- V fragments (time-share regs with kf; overlap reads with softmax) ----
    short8 vf0[4], vf1[4];
#pragma unroll
    for (int ks = 0; ks < 4; ++ks) {
      vf0[ks] = *(const short8*)&Vls[cur][koff0[ks]];
      vf1[ks] = *(const short8*)&Vls[cur][koff1[ks]];
    }

    // ---- in-register online softmax (log2 domain) ----
#define MAX4(a,b,c,d) fmaxf(fmaxf((a),(b)), fmaxf((c),(d)))
    float t0 = MAX4(st0[0], st0[1], st0[2], st0[3]);
    float t1 = MAX4(st0[4], st0[5], st0[6], st0[7]);
    float t2 = MAX4(st0[8], st0[9], st0[10], st0[11]);
    float t3 = MAX4(st0[12], st0[13], st0[14], st0[15]);
    float u0 = MAX4(st1[0], st1[1], st1[2], st1[3]);
    float u1 = MAX4(st1[4], st1[5], st1[6], st1[7]);
    float u2 = MAX4(st1[8], st1[9], st1[10], st1[11]);
    float u3 = MAX4(st1[12], st1[13], st1[14], st1[15]);
    float pmaxh = fmaxf(MAX4(t0, t1, t2, t3), MAX4(u0, u1, u2, u3));
    // cross-half combine via permlane32_swap (VALU, no LDS)
    uint2v msw = __builtin_amdgcn_permlane32_swap(__builtin_bit_cast(unsigned, pmaxh),
                                                  __builtin_bit_cast(unsigned, pmaxh),
                                                  false, false);
    float pmax = fmaxf(__builtin_bit_cast(float, msw[0]), __builtin_bit_cast(float, msw[1]));
    // defer-max: only rescale when running max grew by > 8 (log2) => P bounded by 2^8
    if (!__all(pmax - m <= 8.0f)) {
      float mnew = fmaxf(m, pmax);
      float alpha = exp2f(m - mnew);
      m = mnew;
      lsum *= alpha;
#pragma unroll
      for (int r = 0; r < 16; ++r) { ot0[r] *= alpha; ot1[r] *= alpha; }
    }

    // ---- two-phase P = exp2(S - m), sum, and pack to PV B-operand ----
    short8 pb[4];
    float p[16];
    // phase A: st0 -> pb[0], pb[1]
#pragma unroll
    for (int r = 0; r < 16; ++r) p[r] = exp2f(st0[r] - m);
    lsum += (((p[0]+p[1])+(p[2]+p[3])) + ((p[4]+p[5])+(p[6]+p[7])))
          + (((p[8]+p[9])+(p[10]+p[11])) + ((p[12]+p[13])+(p[14]+p[15])));
    {
      unsigned x0 = cvtpk(p[0], p[1]),  x1 = cvtpk(p[2], p[3]);
      unsigned y0 = cvtpk(p[4], p[5]),  y1 = cvtpk(p[6], p[7]);
      uint2v sw0 = __builtin_amdgcn_permlane32_swap(x0, y0, false, false);
      uint2v sw1 = __builtin_amdgcn_permlane32_swap(x1, y1, false, false);
      uint4v pk; pk[0] = sw0[0]; pk[1] = sw1[0]; pk[2] = sw0[1]; pk[3] = sw1[1];
      pb[0] = __builtin_bit_cast(short8, pk);
      unsigned x2 = cvtpk(p[8], p[9]),  x3 = cvtpk(p[10], p[11]);
      unsigned y2 = cvtpk(p[12], p[13]), y3 = cvtpk(p[14], p[15]);
      uint2v sw2 = __builtin_amdgcn_permlane32_swap(x2, y2, false, false);
      uint2v sw3 = __builtin_amdgcn_permlane32_swap(x3, y3, false, false);
      uint4v pk1; pk1[0] = sw2[0]; pk1[1] = sw3[0]; pk1[2] = sw2[1]; pk1[3] = sw3[1];
      pb[1] = __builtin_bit_cast(short8, pk1);
    }
    // phase B: st1 -> pb[2], pb[3] (reuses p[] registers)
#pragma unroll
    for (int r = 0; r < 16; ++r) p[r] = exp2f(st1[r] - m);
    lsum += (((p[0]+p[1])+(p[2]+p[3])) + ((p[4]+p[5])+(p[6]+p[7])))
          + (((p[8]+p[9])+(p[10]+p[11])) + ((p[12]+p[13])+(p[14]+p[15])));
    {
      unsigned x0 = cvtpk(p[0], p[1]),  x1 = cvtpk(p[2], p[3]);
      unsigned y0 = cvtpk(p[4], p[5]),  y1 = cvtpk(p[6], p[7]);
      uint2v sw0 = __builtin_amdgcn_permlane32_swap(x0, y0, false, false);
      uint2v sw1 = __builtin_amdgcn_permlane32_swap(x1, y1, false, false);
      uint4v pk; pk[0] = sw0[0]; pk[1] = sw1[0]; pk[2] = sw0[1]; pk[3] = sw1[1];
      pb[2] = __builtin_bit_cast(short8, pk);
      unsigned x2 = cvtpk(p[8], p[9]),  x3 = cvtpk(p[10], p[11]);
      unsigned y2 = cvtpk(p[12], p[13]), y3 = cvtpk(p[14], p[15]);
      uint2v sw2 = __builtin_amdgcn_permlane32_swap(x2, y2, false, false);
      uint2v sw3 = __builtin_amdgcn_permlane32_swap(x3, y3, false, false);
      uint4v pk1; pk1[0] = sw2[0]; pk1[1] = sw3[0]; pk1[2] = sw2[1]; pk1[3] = sw3[1];
      pb[3] = __builtin_bit_cast(short8, pk1);
    }

    // ---- PV ----
    __builtin_amdgcn_s_setprio(1);
#pragma unroll
    for (int ks = 0; ks < 4; ++ks) {
      ot0 = MFMA32(vf0[ks], pb[ks], ot0);
      ot1 = MFMA32(vf1[ks], pb[ks], ot1);
    }
    __builtin_amdgcn_s_setprio(0);

    // next-tile staging done + all waves done reading cur -> flip buffers
    __syncthreads();
  }

  // ---- finalize: combine per-half lsum, /lsum, store bf16 [token][h*64+d] ----
  uint2v lsw = __builtin_amdgcn_permlane32_swap(__builtin_bit_cast(unsigned, lsum),
                                                __builtin_bit_cast(unsigned, lsum),
                                                false, false);
  float ltot = __builtin_bit_cast(float, lsw[0]) + __builtin_bit_cast(float, lsw[1]);
  float inv = 1.0f / ltot;
  int b = bh >> 4, h = bh & 15;
  unsigned short* orow = attn_out + ((size_t)(b * 2048 + qi)) * 1024 + h * 64 + 4 * hi;
#pragma unroll
  for (int g = 0; g < 4; ++g) {
    uint2v u0, u1;
    u0[0] = cvtpk(ot0[4*g + 0] * inv, ot0[4*g + 1] * inv);
    u0[1] = cvtpk(ot0[4*g + 2] * inv, ot0[4*g + 3] * inv);
    u1[0] = cvtpk(ot1[4*g + 0] * inv, ot1[4*g + 1] * inv);
    u1[1] = cvtpk(ot1[4*g + 2] * inv, ot1[4*g + 3] * inv);
    *(uint2v*)(orow + 8 * g) = u0;         // d = 8g+4hi+0..3
    *(uint2v*)(orow + 32 + 8 * g) = u1;    // d = 32+8g+4hi+0..3
  }
}

extern "C" void kernel_launch(void* const* d_in, const int* in_sizes, int n_in,
                              void* d_out, int out_size, void* d_ws, size_t ws_size,
                              hipStream_t stream) {
  (void)in_sizes; (void)n_in; (void)out_size; (void)ws_size;
  const float* x     = (const float*)d_in[0];
  const float* W_qkv = (const float*)d_in[1];
  const float* b_qkv = (const float*)d_in[2];
  const float* W_out = (const float*)d_in[3];
  const float* b_out = (const float*)d_in[4];
  float* out = (float*)d_out;
  char* ws = (char*)d_ws;
  unsigned short* xb    = (unsigned short*)(ws);             // 8192x1024 bf16
  unsigned short* WqkvT = (unsigned short*)(ws + 16777216);  // 3072x1024 bf16
  unsigned short* WoutT = (unsigned short*)(ws + 23068672);  // 1024x1024 bf16
  unsigned short* Qb    = (unsigned short*)(ws + 25165824);  // 64x2048x64 bf16
  unsigned short* Kb    = (unsigned short*)(ws + 41943040);  // 64x2048x64 bf16
  unsigned short* Vb    = (unsigned short*)(ws + 58720256);  // 64x2048x64 bf16
  unsigned short* Vtb   = (unsigned short*)(ws + 75497472);  // 64x64x2048 bf16
  unsigned short* attnb = (unsigned short*)(ws + 92274688);  // 8192x1024 bf16

  cvt_f32_bf16<<<8192, 256, 0, stream>>>(x, xb);
  cvt_transpose<<<dim3(16, 48), 256, 0, stream>>>(W_qkv, WqkvT, 1024, 3072);
  cvt_transpose<<<dim3(16, 16), 256, 0, stream>>>(W_out, WoutT, 1024, 1024);
  gemm_qkv<<<dim3(64, 24), 256, 0, stream>>>(xb, WqkvT, b_qkv, Qb, Kb, Vb);
  transpose_v<<<dim3(64, 32), 256, 0, stream>>>(Vb, Vtb);
  attn_fwd2<<<1024, 256, 0, stream>>>(Qb, Kb, Vtb, attnb);
  gemm_out<<<dim3(64, 8), 256, 0, stream>>>(attnb, WoutT, b_out, out);
}

// Round 4
// 230.408 us; speedup vs baseline: 1.2072x; 1.2072x over previous
//
#include <hip/hip_runtime.h>
#include <stdint.h>

typedef __attribute__((ext_vector_type(8))) short short8;
typedef __attribute__((ext_vector_type(4))) float f32x4;
typedef __attribute__((ext_vector_type(16))) float f32x16;
typedef __attribute__((ext_vector_type(4))) float float4v;
typedef __attribute__((ext_vector_type(4))) unsigned short ushort4v;
typedef __attribute__((ext_vector_type(2))) unsigned int uint2v;
typedef __attribute__((ext_vector_type(4))) unsigned int uint4v;

#define MFMA16(a,b,c) __builtin_amdgcn_mfma_f32_16x16x32_bf16((a),(b),(c),0,0,0)
#define MFMA32(a,b,c) __builtin_amdgcn_mfma_f32_32x32x16_bf16((a),(b),(c),0,0,0)

typedef const __attribute__((address_space(1))) void gld_src_t;
typedef __attribute__((address_space(3))) void gld_dst_t;
#define GLOAD_LDS16(g, l) __builtin_amdgcn_global_load_lds((gld_src_t*)(g), (gld_dst_t*)(l), 16, 0, 0)

__device__ __forceinline__ unsigned short f2bf(float f) {
  union { float f; unsigned int u; } v; v.f = f;
  unsigned int u = v.u;
  unsigned int r = (u + 0x7fffu + ((u >> 16) & 1u)) >> 16;  // RNE
  return (unsigned short)r;
}

// hardware packed f32x2 -> bf16x2 (RNE), low = a, high = b
__device__ __forceinline__ unsigned cvtpk(float a, float b) {
  unsigned r;
  asm("v_cvt_pk_bf16_f32 %0, %1, %2" : "=v"(r) : "v"(a), "v"(b));
  return r;
}

// ---------------- convert fp32 -> bf16, vectorized ----------------
__global__ __launch_bounds__(256) void cvt_f32_bf16(const float* __restrict__ in,
                                                    unsigned short* __restrict__ out) {
  int i = blockIdx.x * 256 + threadIdx.x;
  float4v v = ((const float4v*)in)[i];
  ushort4v o;
  o[0] = f2bf(v[0]); o[1] = f2bf(v[1]); o[2] = f2bf(v[2]); o[3] = f2bf(v[3]);
  ((ushort4v*)out)[i] = o;
}

// ------------- transpose+convert W [K][N] f32 -> WT [N][K] bf16 -------------
__global__ __launch_bounds__(256) void cvt_transpose(const float* __restrict__ W,
                                                     unsigned short* __restrict__ WT,
                                                     int K, int N) {
  __shared__ unsigned short lds[64][72];
  int k0 = blockIdx.x * 64, n0 = blockIdx.y * 64;
  int t = threadIdx.x, tr = t >> 4, tc = t & 15;
#pragma unroll
  for (int p = 0; p < 4; ++p) {
    int k = tr + p * 16;
    float4v v = *(const float4v*)&W[(size_t)(k0 + k) * N + n0 + tc * 4];
    lds[tc * 4 + 0][k] = f2bf(v[0]);
    lds[tc * 4 + 1][k] = f2bf(v[1]);
    lds[tc * 4 + 2][k] = f2bf(v[2]);
    lds[tc * 4 + 3][k] = f2bf(v[3]);
  }
  __syncthreads();
#pragma unroll
  for (int p = 0; p < 4; ++p) {
    int n = tr + p * 16;
    ushort4v o;
    o[0] = lds[n][tc * 4 + 0]; o[1] = lds[n][tc * 4 + 1];
    o[2] = lds[n][tc * 4 + 2]; o[3] = lds[n][tc * 4 + 3];
    *(ushort4v*)&WT[(size_t)(n0 + n) * K + k0 + tc * 4] = o;
  }
}

// ------------- transpose V [bh][s][64] -> Vt [bh][64][s] (bf16) -------------
__global__ __launch_bounds__(256) void transpose_v(const unsigned short* __restrict__ V,
                                                   unsigned short* __restrict__ Vt) {
  __shared__ unsigned short lds[64][72];
  int bh = blockIdx.x, s0 = blockIdx.y * 64;
  int t = threadIdx.x, tr = t >> 4, tc = t & 15;
  const unsigned short* Vb = V + (size_t)bh * 2048 * 64;
  unsigned short* Vtb = Vt + (size_t)bh * 64 * 2048;
#pragma unroll
  for (int p = 0; p < 4; ++p) {
    int s = tr + p * 16;
    ushort4v v = *(const ushort4v*)&Vb[(size_t)(s0 + s) * 64 + tc * 4];
    lds[tc * 4 + 0][s] = v[0];
    lds[tc * 4 + 1][s] = v[1];
    lds[tc * 4 + 2][s] = v[2];
    lds[tc * 4 + 3][s] = v[3];
  }
  __syncthreads();
#pragma unroll
  for (int p = 0; p < 4; ++p) {
    int d = tr + p * 16;
    ushort4v o;
    o[0] = lds[d][tc * 4 + 0]; o[1] = lds[d][tc * 4 + 1];
    o[2] = lds[d][tc * 4 + 2]; o[3] = lds[d][tc * 4 + 3];
    *(ushort4v*)&Vtb[(size_t)d * 2048 + s0 + tc * 4] = o;
  }
}

// ---------------- shared 128x128 bf16 GEMM mainloop (m97 structure) ----------------
__device__ __forceinline__ void gemm_mainloop_128(const unsigned short* __restrict__ A,
                                                  const unsigned short* __restrict__ BT,
                                                  int K, int row0, int col0,
                                                  unsigned short* Als, unsigned short* Bls,
                                                  f32x4 acc[4][4]) {
  int t = threadIdx.x;
  int w = t >> 6, l = t & 63;
  int lo = l & 15, hi = l >> 4;
  int wr = w >> 1, wc = w & 1;
  const unsigned short* Ag1 = A + (size_t)(row0 + (t >> 2)) * K + (t & 3) * 8;
  const unsigned short* Ag2 = A + (size_t)(row0 + 64 + (t >> 2)) * K + (t & 3) * 8;
  const unsigned short* Bg1 = BT + (size_t)(col0 + (t >> 2)) * K + (t & 3) * 8;
  const unsigned short* Bg2 = BT + (size_t)(col0 + 64 + (t >> 2)) * K + (t & 3) * 8;
  unsigned short* Ald1 = Als + w * 512;
  unsigned short* Ald2 = Als + 2048 + w * 512;
  unsigned short* Bld1 = Bls + w * 512;
  unsigned short* Bld2 = Bls + 2048 + w * 512;
  int aoff[4], boff[4];
#pragma unroll
  for (int m = 0; m < 4; ++m) aoff[m] = (wr * 64 + m * 16 + lo) * 32 + hi * 8;
#pragma unroll
  for (int n = 0; n < 4; ++n) boff[n] = (wc * 64 + n * 16 + lo) * 32 + hi * 8;

  for (int k0 = 0; k0 < K; k0 += 32) {
    GLOAD_LDS16(Ag1 + k0, Ald1);
    GLOAD_LDS16(Ag2 + k0, Ald2);
    GLOAD_LDS16(Bg1 + k0, Bld1);
    GLOAD_LDS16(Bg2 + k0, Bld2);
    __syncthreads();
    short8 af[4], bf[4];
#pragma unroll
    for (int m = 0; m < 4; ++m) af[m] = *(const short8*)&Als[aoff[m]];
#pragma unroll
    for (int n = 0; n < 4; ++n) bf[n] = *(const short8*)&Bls[boff[n]];
#pragma unroll
    for (int m = 0; m < 4; ++m)
#pragma unroll
      for (int n = 0; n < 4; ++n)
        acc[m][n] = MFMA16(af[m], bf[n], acc[m][n]);
    __syncthreads();
  }
}

// -------- GEMM1: xb @ W_qkvT + b -> scatter Q(*0.125*log2e)/K/V [bh][s][64] --------
__global__ __launch_bounds__(256) void gemm_qkv(const unsigned short* __restrict__ xb,
                                                const unsigned short* __restrict__ WT,
                                                const float* __restrict__ bias,
                                                unsigned short* __restrict__ Q,
                                                unsigned short* __restrict__ Ko,
                                                unsigned short* __restrict__ V) {
  __shared__ unsigned short Als[4096], Bls[4096];
  f32x4 zero = {0.f, 0.f, 0.f, 0.f};
  f32x4 acc[4][4];
#pragma unroll
  for (int m = 0; m < 4; ++m)
#pragma unroll
    for (int n = 0; n < 4; ++n) acc[m][n] = zero;
  int row0 = blockIdx.x * 128, col0 = blockIdx.y * 128;
  gemm_mainloop_128(xb, WT, 1024, row0, col0, Als, Bls, acc);

  int t = threadIdx.x, w = t >> 6, l = t & 63, lo = l & 15, hi = l >> 4;
  int wr = w >> 1, wc = w & 1;
#pragma unroll
  for (int m = 0; m < 4; ++m) {
#pragma unroll
    for (int n = 0; n < 4; ++n) {
      int col = col0 + wc * 64 + n * 16 + lo;
      float b = bias[col];
      int which = col >> 10, hd = col & 1023, h = hd >> 6, d = hd & 63;
#pragma unroll
      for (int r = 0; r < 4; ++r) {
        int row = row0 + wr * 64 + m * 16 + hi * 4 + r;
        int bb = row >> 11, s = row & 2047;
        float v = acc[m][n][r] + b;
        size_t dst = ((size_t)(bb * 16 + h) * 2048 + s) * 64 + d;
        if (which == 0)      Q[dst]  = f2bf(v * 0.18033688011112042f);  // 0.125*log2(e)
        else if (which == 1) Ko[dst] = f2bf(v);
        else                 V[dst]  = f2bf(v);
      }
    }
  }
}

// ---------------- GEMM2: attn @ W_outT + b_out -> fp32 out ----------------
__global__ __launch_bounds__(256) void gemm_out(const unsigned short* __restrict__ attn,
                                                const unsigned short* __restrict__ WT,
                                                const float* __restrict__ bias,
                                                float* __restrict__ out) {
  __shared__ unsigned short Als[4096], Bls[4096];
  f32x4 zero = {0.f, 0.f, 0.f, 0.f};
  f32x4 acc[4][4];
#pragma unroll
  for (int m = 0; m < 4; ++m)
#pragma unroll
    for (int n = 0; n < 4; ++n) acc[m][n] = zero;
  int row0 = blockIdx.x * 128, col0 = blockIdx.y * 128;
  gemm_mainloop_128(attn, WT, 1024, row0, col0, Als, Bls, acc);

  int t = threadIdx.x, w = t >> 6, l = t & 63, lo = l & 15, hi = l >> 4;
  int wr = w >> 1, wc = w & 1;
#pragma unroll
  for (int m = 0; m < 4; ++m) {
#pragma unroll
    for (int n = 0; n < 4; ++n) {
      int col = col0 + wc * 64 + n * 16 + lo;
      float b = bias[col];
#pragma unroll
      for (int r = 0; r < 4; ++r) {
        int row = row0 + wr * 64 + m * 16 + hi * 4 + r;
        out[(size_t)row * 1024 + col] = acc[m][n][r] + b;
      }
    }
  }
}

// ===== flash attention v6: 4-buffer counted-vmcnt pipeline, 2 blocks/CU (L2-fit) =====
// v5 post-mortem: 4 blocks/CU made all 1024 blocks resident -> 8 bh x 512KB = 4MB
// KV per XCD = entire L2 + streaming Q/out -> thrash (FETCH 25->148MB), and the
// per-iter __syncthreads (vmcnt(0) drain) turned every L2 miss into an all-wave stall.
// v6: (a) 64KB LDS/block hard-caps residency at 2 blocks/CU -> 4 bh/XCD = 2MB, L2-fit;
// (b) T3/T4 pipeline: 4 buffers, 3 tiles in flight, ONE raw s_barrier per iter with
// s_waitcnt vmcnt(8) -- waits only the tile staged 3 iters ago (~5k cyc cover), never
// drains newer stages. Safety: a wave's ds_reads of buf X are reg-consumed (lgkmcnt)
// before it enters the barrier, so post-barrier staging into the rotated-out buffer
// cannot overwrite live data; vmcnt retires in order so vmcnt(8) with 12 outstanding
// completes exactly the oldest stage batch. Keeps: conflict-free XOR swizzle
// (slot = chunk ^ (row&7) ^ (row>>3)), defer-max, permlane softmax, setprio.
__global__ __launch_bounds__(256, 2) void attn_fwd2(const unsigned short* __restrict__ Q,
                                                    const unsigned short* __restrict__ Kg,
                                                    const unsigned short* __restrict__ Vt,
                                                    unsigned short* __restrict__ attn_out) {
  const int S = 2048;
  __shared__ unsigned short Kls[4][4096];   // [buf][64 rows][8 slots x 16B] swizzled
  __shared__ unsigned short Vls[4][4096];   // [buf][64 d   ][8 slots x 16B] swizzled

  int bid = blockIdx.x;
  int swz = (bid & 7) * 128 + (bid >> 3);   // 8 bh per XCD; 2 blocks/CU -> 4 bh resident
  int bh = swz >> 4, qt = swz & 15;
  int t = threadIdx.x, w = t >> 6, l = t & 63;
  int lo = l & 31, hi = l >> 5;
  int qi = qt * 128 + w * 32 + lo;
  const unsigned short* Qr = Q + ((size_t)bh * S + qi) * 64 + hi * 8;
  const char* KbB = (const char*)(Kg + (size_t)bh * S * 64);
  const char* VbB = (const char*)(Vt + (size_t)bh * 64 * S);

  short8 qf[4];
#pragma unroll
  for (int ks = 0; ks < 4; ++ks) qf[ks] = *(const short8*)(Qr + ks * 16);

  // ---- staging geometry: 16 gload_lds per tile (4/wave), 1KB contiguous each ----
  // instr j (j=0..7 per tensor) covers tile rows 8j..8j+7; lane l writes LDS byte
  // j*1024 + l*16 = (row 8j+(l>>3), slot l&7). Stored layout: slot = g ^ s(row),
  // s(row) = (row&7)^(row>>3). => source global chunk g = (l&7) ^ (l>>3) ^ j.
  int lrow = l >> 3;                                     // 0..7 (row&7 within instr)
  int j0 = w * 2;                                        // this wave's 2 K + 2 V instrs
  int g0B = (((l & 7) ^ lrow ^ j0) << 4);                // source chunk bytes, instr j0
  int g1B = (((l & 7) ^ lrow ^ (j0 + 1)) << 4);          // source chunk bytes, instr j0+1
  size_t kg0 = (size_t)(8 * j0 + lrow) * 128 + g0B;      // + kv0*128
  size_t kg1 = (size_t)(8 * j0 + 8 + lrow) * 128 + g1B;
  size_t vg0 = (size_t)(8 * j0 + lrow) * 4096 + g0B;     // + kv0*2
  size_t vg1 = (size_t)(8 * j0 + 8 + lrow) * 4096 + g1B;

  // ---- fragment read offsets (ushort idx), loop-invariant ----
  // want global (row, chunk=2ks+hi) -> LDS[row][(2ks+hi) ^ s(row)]
  int koff0[4], koff1[4];
#pragma unroll
  for (int ks = 0; ks < 4; ++ks) {
    int srow = (lo & 7) ^ (lo >> 3);
    koff0[ks] = lo * 64 + (((2 * ks + hi) ^ srow) << 3);
    koff1[ks] = (lo + 32) * 64 + (((2 * ks + hi) ^ srow ^ 4) << 3);
  }

#define STAGE_KV(Kd, Vd, kvoff) do {                                  \
    GLOAD_LDS16(KbB + (size_t)(kvoff) * 128 + kg0, (Kd) + j0 * 512);  \
    GLOAD_LDS16(KbB + (size_t)(kvoff) * 128 + kg1, (Kd) + (j0 + 1) * 512); \
    GLOAD_LDS16(VbB + (size_t)(kvoff) * 2 + vg0, (Vd) + j0 * 512);    \
    GLOAD_LDS16(VbB + (size_t)(kvoff) * 2 + vg1, (Vd) + (j0 + 1) * 512); \
  } while (0)

  // rotating buffer pointers: read Kc/Vc, stage 3-ahead into K3/V3
  unsigned short *Kc = &Kls[0][0], *K1 = &Kls[1][0], *K2 = &Kls[2][0], *K3 = &Kls[3][0];
  unsigned short *Vc = &Vls[0][0], *V1 = &Vls[1][0], *V2 = &Vls[2][0], *V3 = &Vls[3][0];

  // ---- prologue: stage tiles 0,1,2 (12 loads/wave in flight) ----
  STAGE_KV(Kc, Vc, 0);
  STAGE_KV(K1, V1, 64);
  STAGE_KV(K2, V2, 128);

  const f32x16 zf = {0.f,0.f,0.f,0.f,0.f,0.f,0.f,0.f,0.f,0.f,0.f,0.f,0.f,0.f,0.f,0.f};
  f32x16 ot0 = zf, ot1 = zf;
  float m = -1e30f, lsum = 0.f;   // lsum is PER-HALF; combined in epilogue

  for (int it = 0; it < 32; ++it) {
    // wait ONLY for the tile staged 3 iters ago (8 newer loads stay in flight)
    asm volatile("s_waitcnt vmcnt(8)" ::: "memory");
    __builtin_amdgcn_s_barrier();
    // stage tile it+3 into the buffer last read at iter it-1 (wrap: harmless re-stage)
    STAGE_KV(K3, V3, ((it + 3) & 31) * 64);

    // ---- K fragments from LDS (conflict-free swizzled b128 reads) ----
    short8 kf0[4], kf1[4];
#pragma unroll
    for (int ks = 0; ks < 4; ++ks) {
      kf0[ks] = *(const short8*)&Kc[koff0[ks]];
      kf1[ks] = *(const short8*)&Kc[koff1[ks]];
    }
    f32x16 st0 = zf, st1 = zf;
    __builtin_amdgcn_s_setprio(1);
#pragma unroll
    for (int ks = 0; ks < 4; ++ks) {
      st0 = MFMA32(kf0[ks], qf[ks], st0);
      st1 = MFMA32(kf1[ks], qf[ks], st1);
    }
    __builtin_amdgcn_s_setprio(0);
    // ---- V fragments (time-share regs with kf; overlap reads with softmax) ----
    short8 vf0[4], vf1[4];
#pragma unroll
    for (int ks = 0; ks < 4; ++ks) {
      vf0[ks] = *(const short8*)&Vc[koff0[ks]];
      vf1[ks] = *(const short8*)&Vc[koff1[ks]];
    }

    // ---- in-register online softmax (log2 domain) ----
#define MAX4(a,b,c,d) fmaxf(fmaxf((a),(b)), fmaxf((c),(d)))
    float t0 = MAX4(st0[0], st0[1], st0[2], st0[3]);
    float t1 = MAX4(st0[4], st0[5], st0[6], st0[7]);
    float t2 = MAX4(st0[8], st0[9], st0[10], st0[11]);
    float t3 = MAX4(st0[12], st0[13], st0[14], st0[15]);
    float u0 = MAX4(st1[0], st1[1], st1[2], st1[3]);
    float u1 = MAX4(st1[4], st1[5], st1[6], st1[7]);
    float u2 = MAX4(st1[8], st1[9], st1[10], st1[11]);
    float u3 = MAX4(st1[12], st1[13], st1[14], st1[15]);
    float pmaxh = fmaxf(MAX4(t0, t1, t2, t3), MAX4(u0, u1, u2, u3));
    // cross-half combine via permlane32_swap (VALU, no LDS)
    uint2v msw = __builtin_amdgcn_permlane32_swap(__builtin_bit_cast(unsigned, pmaxh),
                                                  __builtin_bit_cast(unsigned, pmaxh),
                                                  false, false);
    float pmax = fmaxf(__builtin_bit_cast(float, msw[0]), __builtin_bit_cast(float, msw[1]));
    // defer-max: only rescale when running max grew by > 8 (log2) => P bounded by 2^8
    if (!__all(pmax - m <= 8.0f)) {
      float mnew = fmaxf(m, pmax);
      float alpha = exp2f(m - mnew);
      m = mnew;
      lsum *= alpha;
#pragma unroll
      for (int r = 0; r < 16; ++r) { ot0[r] *= alpha; ot1[r] *= alpha; }
    }

    // ---- two-phase P = exp2(S - m), sum, and pack to PV B-operand ----
    short8 pb[4];
    float p[16];
    // phase A: st0 -> pb[0], pb[1]
#pragma unroll
    for (int r = 0; r < 16; ++r) p[r] = exp2f(st0[r] - m);
    lsum += (((p[0]+p[1])+(p[2]+p[3])) + ((p[4]+p[5])+(p[6]+p[7])))
          + (((p[8]+p[9])+(p[10]+p[11])) + ((p[12]+p[13])+(p[14]+p[15])));
    {
      unsigned x0 = cvtpk(p[0], p[1]),  x1 = cvtpk(p[2], p[3]);
      unsigned y0 = cvtpk(p[4], p[5]),  y1 = cvtpk(p[6], p[7]);
      uint2v sw0 = __builtin_amdgcn_permlane32_swap(x0, y0, false, false);
      uint2v sw1 = __builtin_amdgcn_permlane32_swap(x1, y1, false, false);
      uint4v pk; pk[0] = sw0[0]; pk[1] = sw1[0]; pk[2] = sw0[1]; pk[3] = sw1[1];
      pb[0] = __builtin_bit_cast(short8, pk);
      unsigned x2 = cvtpk(p[8], p[9]),  x3 = cvtpk(p[10], p[11]);
      unsigned y2 = cvtpk(p[12], p[13]), y3 = cvtpk(p[14], p[15]);
      uint2v sw2 = __builtin_amdgcn_permlane32_swap(x2, y2, false, false);
      uint2v sw3 = __builtin_amdgcn_permlane32_swap(x3, y3, false, false);
      uint4v pk1; pk1[0] = sw2[0]; pk1[1] = sw3[0]; pk1[2] = sw2[1]; pk1[3] = sw3[1];
      pb[1] = __builtin_bit_cast(short8, pk1);
    }
    // phase B: st1 -> pb[2], pb[3] (reuses p[] registers)
#pragma unroll
    for (int r = 0; r < 16; ++r) p[r] = exp2f(st1[r] - m);
    lsum += (((p[0]+p[1])+(p[2]+p[3])) + ((p[4]+p[5])+(p[6]+p[7])))
          + (((p[8]+p[9])+(p[10]+p[11])) + ((p[12]+p[13])+(p[14]+p[15])));
    {
      unsigned x0 = cvtpk(p[0], p[1]),  x1 = cvtpk(p[2], p[3]);
      unsigned y0 = cvtpk(p[4], p[5]),  y1 = cvtpk(p[6], p[7]);
      uint2v sw0 = __builtin_amdgcn_permlane32_swap(x0, y0, false, false);
      uint2v sw1 = __builtin_amdgcn_permlane32_swap(x1, y1, false, false);
      uint4v pk; pk[0] = sw0[0]; pk[1] = sw1[0]; pk[2] = sw0[1]; pk[3] = sw1[1];
      pb[2] = __builtin_bit_cast(short8, pk);
      unsigned x2 = cvtpk(p[8], p[9]),  x3 = cvtpk(p[10], p[11]);
      unsigned y2 = cvtpk(p[12], p[13]), y3 = cvtpk(p[14], p[15]);
      uint2v sw2 = __builtin_amdgcn_permlane32_swap(x2, y2, false, false);
      uint2v sw3 = __builtin_amdgcn_permlane32_swap(x3, y3, false, false);
      uint4v pk1; pk1[0] = sw2[0]; pk1[1] = sw3[0]; pk1[2] = sw2[1]; pk1[3] = sw3[1];
      pb[3] = __builtin_bit_cast(short8, pk1);
    }

    // ---- PV ----
    __builtin_amdgcn_s_setprio(1);
#pragma unroll
    for (int ks = 0; ks < 4; ++ks) {
      ot0 = MFMA32(vf0[ks], pb[ks], ot0);
      ot1 = MFMA32(vf1[ks], pb[ks], ot1);
    }
    __builtin_amdgcn_s_setprio(0);

    // rotate buffers: (cur,1,2,3) -> (1,2,3,cur)
    unsigned short* tk = Kc; Kc = K1; K1 = K2; K2 = K3; K3 = tk;
    unsigned short* tv = Vc; Vc = V1; V1 = V2; V2 = V3; V3 = tv;
  }

  // ---- finalize: combine per-half lsum, /lsum, store bf16 [token][h*64+d] ----
  uint2v lsw = __builtin_amdgcn_permlane32_swap(__builtin_bit_cast(unsigned, lsum),
                                                __builtin_bit_cast(unsigned, lsum),
                                                false, false);
  float ltot = __builtin_bit_cast(float, lsw[0]) + __builtin_bit_cast(float, lsw[1]);
  float inv = 1.0f / ltot;
  int b = bh >> 4, h = bh & 15;
  unsigned short* orow = attn_out + ((size_t)(b * 2048 + qi)) * 1024 + h * 64 + 4 * hi;
#pragma unroll
  for (int g = 0; g < 4; ++g) {
    uint2v u0, u1;
    u0[0] = cvtpk(ot0[4*g + 0] * inv, ot0[4*g + 1] * inv);
    u0[1] = cvtpk(ot0[4*g + 2] * inv, ot0[4*g + 3] * inv);
    u1[0] = cvtpk(ot1[4*g + 0] * inv, ot1[4*g + 1] * inv);
    u1[1] = cvtpk(ot1[4*g + 2] * inv, ot1[4*g + 3] * inv);
    *(uint2v*)(orow + 8 * g) = u0;         // d = 8g+4hi+0..3
    *(uint2v*)(orow + 32 + 8 * g) = u1;    // d = 32+8g+4hi+0..3
  }
}

extern "C" void kernel_launch(void* const* d_in, const int* in_sizes, int n_in,
                              void* d_out, int out_size, void* d_ws, size_t ws_size,
                              hipStream_t stream) {
  (void)in_sizes; (void)n_in; (void)out_size; (void)ws_size;
  const float* x     = (const float*)d_in[0];
  const float* W_qkv = (const float*)d_in[1];
  const float* b_qkv = (const float*)d_in[2];
  const float* W_out = (const float*)d_in[3];
  const float* b_out = (const float*)d_in[4];
  float* out = (float*)d_out;
  char* ws = (char*)d_ws;
  unsigned short* xb    = (unsigned short*)(ws);             // 8192x1024 bf16
  unsigned short* WqkvT = (unsigned short*)(ws + 16777216);  // 3072x1024 bf16
  unsigned short* WoutT = (unsigned short*)(ws + 23068672);  // 1024x1024 bf16
  unsigned short* Qb    = (unsigned short*)(ws + 25165824);  // 64x2048x64 bf16
  unsigned short* Kb    = (unsigned short*)(ws + 41943040);  // 64x2048x64 bf16
  unsigned short* Vb    = (unsigned short*)(ws + 58720256);  // 64x2048x64 bf16
  unsigned short* Vtb   = (unsigned short*)(ws + 75497472);  // 64x64x2048 bf16
  unsigned short* attnb = (unsigned short*)(ws + 92274688);  // 8192x1024 bf16

  cvt_f32_bf16<<<8192, 256, 0, stream>>>(x, xb);
  cvt_transpose<<<dim3(16, 48), 256, 0, stream>>>(W_qkv, WqkvT, 1024, 3072);
  cvt_transpose<<<dim3(16, 16), 256, 0, stream>>>(W_out, WoutT, 1024, 1024);
  gemm_qkv<<<dim3(64, 24), 256, 0, stream>>>(xb, WqkvT, b_qkv, Qb, Kb, Vb);
  transpose_v<<<dim3(64, 32), 256, 0, stream>>>(Vb, Vtb);
  attn_fwd2<<<1024, 256, 0, stream>>>(Qb, Kb, Vtb, attnb);
  gemm_out<<<dim3(64, 8), 256, 0, stream>>>(attnb, WoutT, b_out, out);
}

// Round 5
// 228.063 us; speedup vs baseline: 1.2196x; 1.0103x over previous
//
#include <hip/hip_runtime.h>
#include <stdint.h>

typedef __attribute__((ext_vector_type(8))) short short8;
typedef __attribute__((ext_vector_type(4))) float f32x4;
typedef __attribute__((ext_vector_type(16))) float f32x16;
typedef __attribute__((ext_vector_type(4))) float float4v;
typedef __attribute__((ext_vector_type(4))) unsigned short ushort4v;
typedef __attribute__((ext_vector_type(2))) unsigned int uint2v;
typedef __attribute__((ext_vector_type(4))) unsigned int uint4v;

#define MFMA16(a,b,c) __builtin_amdgcn_mfma_f32_16x16x32_bf16((a),(b),(c),0,0,0)
#define MFMA32(a,b,c) __builtin_amdgcn_mfma_f32_32x32x16_bf16((a),(b),(c),0,0,0)

typedef const __attribute__((address_space(1))) void gld_src_t;
typedef __attribute__((address_space(3))) void gld_dst_t;
#define GLOAD_LDS16(g, l) __builtin_amdgcn_global_load_lds((gld_src_t*)(g), (gld_dst_t*)(l), 16, 0, 0)

__device__ __forceinline__ unsigned short f2bf(float f) {
  union { float f; unsigned int u; } v; v.f = f;
  unsigned int u = v.u;
  unsigned int r = (u + 0x7fffu + ((u >> 16) & 1u)) >> 16;  // RNE
  return (unsigned short)r;
}

// hardware packed f32x2 -> bf16x2 (RNE), low = a, high = b
__device__ __forceinline__ unsigned cvtpk(float a, float b) {
  unsigned r;
  asm("v_cvt_pk_bf16_f32 %0, %1, %2" : "=v"(r) : "v"(a), "v"(b));
  return r;
}

// single-instruction 3-input max (VOP3, register operands only)
__device__ __forceinline__ float max3f(float a, float b, float c) {
  float d;
  asm("v_max3_f32 %0, %1, %2, %3" : "=v"(d) : "v"(a), "v"(b), "v"(c));
  return d;
}

// ---------------- convert fp32 -> bf16, vectorized ----------------
__global__ __launch_bounds__(256) void cvt_f32_bf16(const float* __restrict__ in,
                                                    unsigned short* __restrict__ out) {
  int i = blockIdx.x * 256 + threadIdx.x;
  float4v v = ((const float4v*)in)[i];
  ushort4v o;
  o[0] = f2bf(v[0]); o[1] = f2bf(v[1]); o[2] = f2bf(v[2]); o[3] = f2bf(v[3]);
  ((ushort4v*)out)[i] = o;
}

// ------------- transpose+convert W [K][N] f32 -> WT [N][K] bf16 -------------
__global__ __launch_bounds__(256) void cvt_transpose(const float* __restrict__ W,
                                                     unsigned short* __restrict__ WT,
                                                     int K, int N) {
  __shared__ unsigned short lds[64][72];
  int k0 = blockIdx.x * 64, n0 = blockIdx.y * 64;
  int t = threadIdx.x, tr = t >> 4, tc = t & 15;
#pragma unroll
  for (int p = 0; p < 4; ++p) {
    int k = tr + p * 16;
    float4v v = *(const float4v*)&W[(size_t)(k0 + k) * N + n0 + tc * 4];
    lds[tc * 4 + 0][k] = f2bf(v[0]);
    lds[tc * 4 + 1][k] = f2bf(v[1]);
    lds[tc * 4 + 2][k] = f2bf(v[2]);
    lds[tc * 4 + 3][k] = f2bf(v[3]);
  }
  __syncthreads();
#pragma unroll
  for (int p = 0; p < 4; ++p) {
    int n = tr + p * 16;
    ushort4v o;
    o[0] = lds[n][tc * 4 + 0]; o[1] = lds[n][tc * 4 + 1];
    o[2] = lds[n][tc * 4 + 2]; o[3] = lds[n][tc * 4 + 3];
    *(ushort4v*)&WT[(size_t)(n0 + n) * K + k0 + tc * 4] = o;
  }
}

// ------------- transpose V [bh][s][64] -> Vt [bh][64][s] (bf16) -------------
__global__ __launch_bounds__(256) void transpose_v(const unsigned short* __restrict__ V,
                                                   unsigned short* __restrict__ Vt) {
  __shared__ unsigned short lds[64][72];
  int bh = blockIdx.x, s0 = blockIdx.y * 64;
  int t = threadIdx.x, tr = t >> 4, tc = t & 15;
  const unsigned short* Vb = V + (size_t)bh * 2048 * 64;
  unsigned short* Vtb = Vt + (size_t)bh * 64 * 2048;
#pragma unroll
  for (int p = 0; p < 4; ++p) {
    int s = tr + p * 16;
    ushort4v v = *(const ushort4v*)&Vb[(size_t)(s0 + s) * 64 + tc * 4];
    lds[tc * 4 + 0][s] = v[0];
    lds[tc * 4 + 1][s] = v[1];
    lds[tc * 4 + 2][s] = v[2];
    lds[tc * 4 + 3][s] = v[3];
  }
  __syncthreads();
#pragma unroll
  for (int p = 0; p < 4; ++p) {
    int d = tr + p * 16;
    ushort4v o;
    o[0] = lds[d][tc * 4 + 0]; o[1] = lds[d][tc * 4 + 1];
    o[2] = lds[d][tc * 4 + 2]; o[3] = lds[d][tc * 4 + 3];
    *(ushort4v*)&Vtb[(size_t)d * 2048 + s0 + tc * 4] = o;
  }
}

// ---------------- shared 128x128 bf16 GEMM mainloop (m97 structure) ----------------
__device__ __forceinline__ void gemm_mainloop_128(const unsigned short* __restrict__ A,
                                                  const unsigned short* __restrict__ BT,
                                                  int K, int row0, int col0,
                                                  unsigned short* Als, unsigned short* Bls,
                                                  f32x4 acc[4][4]) {
  int t = threadIdx.x;
  int w = t >> 6, l = t & 63;
  int lo = l & 15, hi = l >> 4;
  int wr = w >> 1, wc = w & 1;
  const unsigned short* Ag1 = A + (size_t)(row0 + (t >> 2)) * K + (t & 3) * 8;
  const unsigned short* Ag2 = A + (size_t)(row0 + 64 + (t >> 2)) * K + (t & 3) * 8;
  const unsigned short* Bg1 = BT + (size_t)(col0 + (t >> 2)) * K + (t & 3) * 8;
  const unsigned short* Bg2 = BT + (size_t)(col0 + 64 + (t >> 2)) * K + (t & 3) * 8;
  unsigned short* Ald1 = Als + w * 512;
  unsigned short* Ald2 = Als + 2048 + w * 512;
  unsigned short* Bld1 = Bls + w * 512;
  unsigned short* Bld2 = Bls + 2048 + w * 512;
  int aoff[4], boff[4];
#pragma unroll
  for (int m = 0; m < 4; ++m) aoff[m] = (wr * 64 + m * 16 + lo) * 32 + hi * 8;
#pragma unroll
  for (int n = 0; n < 4; ++n) boff[n] = (wc * 64 + n * 16 + lo) * 32 + hi * 8;

  for (int k0 = 0; k0 < K; k0 += 32) {
    GLOAD_LDS16(Ag1 + k0, Ald1);
    GLOAD_LDS16(Ag2 + k0, Ald2);
    GLOAD_LDS16(Bg1 + k0, Bld1);
    GLOAD_LDS16(Bg2 + k0, Bld2);
    __syncthreads();
    short8 af[4], bf[4];
#pragma unroll
    for (int m = 0; m < 4; ++m) af[m] = *(const short8*)&Als[aoff[m]];
#pragma unroll
    for (int n = 0; n < 4; ++n) bf[n] = *(const short8*)&Bls[boff[n]];
#pragma unroll
    for (int m = 0; m < 4; ++m)
#pragma unroll
      for (int n = 0; n < 4; ++n)
        acc[m][n] = MFMA16(af[m], bf[n], acc[m][n]);
    __syncthreads();
  }
}

// -------- GEMM1: xb @ W_qkvT + b -> scatter Q(*0.125*log2e)/K/V [bh][s][64] --------
__global__ __launch_bounds__(256) void gemm_qkv(const unsigned short* __restrict__ xb,
                                                const unsigned short* __restrict__ WT,
                                                const float* __restrict__ bias,
                                                unsigned short* __restrict__ Q,
                                                unsigned short* __restrict__ Ko,
                                                unsigned short* __restrict__ V) {
  __shared__ unsigned short Als[4096], Bls[4096];
  f32x4 zero = {0.f, 0.f, 0.f, 0.f};
  f32x4 acc[4][4];
#pragma unroll
  for (int m = 0; m < 4; ++m)
#pragma unroll
    for (int n = 0; n < 4; ++n) acc[m][n] = zero;
  int row0 = blockIdx.x * 128, col0 = blockIdx.y * 128;
  gemm_mainloop_128(xb, WT, 1024, row0, col0, Als, Bls, acc);

  int t = threadIdx.x, w = t >> 6, l = t & 63, lo = l & 15, hi = l >> 4;
  int wr = w >> 1, wc = w & 1;
#pragma unroll
  for (int m = 0; m < 4; ++m) {
#pragma unroll
    for (int n = 0; n < 4; ++n) {
      int col = col0 + wc * 64 + n * 16 + lo;
      float b = bias[col];
      int which = col >> 10, hd = col & 1023, h = hd >> 6, d = hd & 63;
#pragma unroll
      for (int r = 0; r < 4; ++r) {
        int row = row0 + wr * 64 + m * 16 + hi * 4 + r;
        int bb = row >> 11, s = row & 2047;
        float v = acc[m][n][r] + b;
        size_t dst = ((size_t)(bb * 16 + h) * 2048 + s) * 64 + d;
        if (which == 0)      Q[dst]  = f2bf(v * 0.18033688011112042f);  // 0.125*log2(e)
        else if (which == 1) Ko[dst] = f2bf(v);
        else                 V[dst]  = f2bf(v);
      }
    }
  }
}

// ---------------- GEMM2: attn @ W_outT + b_out -> fp32 out ----------------
__global__ __launch_bounds__(256) void gemm_out(const unsigned short* __restrict__ attn,
                                                const unsigned short* __restrict__ WT,
                                                const float* __restrict__ bias,
                                                float* __restrict__ out) {
  __shared__ unsigned short Als[4096], Bls[4096];
  f32x4 zero = {0.f, 0.f, 0.f, 0.f};
  f32x4 acc[4][4];
#pragma unroll
  for (int m = 0; m < 4; ++m)
#pragma unroll
    for (int n = 0; n < 4; ++n) acc[m][n] = zero;
  int row0 = blockIdx.x * 128, col0 = blockIdx.y * 128;
  gemm_mainloop_128(attn, WT, 1024, row0, col0, Als, Bls, acc);

  int t = threadIdx.x, w = t >> 6, l = t & 63, lo = l & 15, hi = l >> 4;
  int wr = w >> 1, wc = w & 1;
#pragma unroll
  for (int m = 0; m < 4; ++m) {
#pragma unroll
    for (int n = 0; n < 4; ++n) {
      int col = col0 + wc * 64 + n * 16 + lo;
      float b = bias[col];
#pragma unroll
      for (int r = 0; r < 4; ++r) {
        int row = row0 + wr * 64 + m * 16 + hi * 4 + r;
        out[(size_t)row * 1024 + col] = acc[m][n][r] + b;
      }
    }
  }
}

// ===== flash attention v7: VALU-issue cuts (v6 structure kept) =====
// v6 post-mortem: L2-fit restored (FETCH 148->24.6MB) but dur == v4 -> the kernel
// sits on an issue-throughput plateau, dominated by per-score softmax VALU
// (~550 cyc/wave-iter vs 128 MFMA). v7 removes the two largest removable chunks:
//  1. lsum via ones-MFMA: lacc = MFMA32(ones, pb[ks], lacc) computes sum_k P[k][q]
//     on the 20%-utilized matrix pipe -> deletes ~30 f32 adds/iter + per-half lsum
//     bookkeeping + the epilogue permlane combine. Rescale touches lacc[0] only
//     (other regs never read). Also sums the same bf16 P that PV consumes.
//  2. v_max3_f32 tree: 31 binary fmax -> 16 max3 ops.
// Pipeline unchanged: 4-buffer counted-vmcnt (vmcnt(8)), one s_barrier/iter,
// conflict-free XOR swizzle, defer-max, setprio, 2 blocks/CU (L2-fit).
__global__ __launch_bounds__(256, 2) void attn_fwd2(const unsigned short* __restrict__ Q,
                                                    const unsigned short* __restrict__ Kg,
                                                    const unsigned short* __restrict__ Vt,
                                                    unsigned short* __restrict__ attn_out) {
  const int S = 2048;
  __shared__ unsigned short Kls[4][4096];   // [buf][64 rows][8 slots x 16B] swizzled
  __shared__ unsigned short Vls[4][4096];   // [buf][64 d   ][8 slots x 16B] swizzled

  int bid = blockIdx.x;
  int swz = (bid & 7) * 128 + (bid >> 3);   // 8 bh per XCD; 2 blocks/CU -> 4 bh resident
  int bh = swz >> 4, qt = swz & 15;
  int t = threadIdx.x, w = t >> 6, l = t & 63;
  int lo = l & 31, hi = l >> 5;
  int qi = qt * 128 + w * 32 + lo;
  const unsigned short* Qr = Q + ((size_t)bh * S + qi) * 64 + hi * 8;
  const char* KbB = (const char*)(Kg + (size_t)bh * S * 64);
  const char* VbB = (const char*)(Vt + (size_t)bh * 64 * S);

  short8 qf[4];
#pragma unroll
  for (int ks = 0; ks < 4; ++ks) qf[ks] = *(const short8*)(Qr + ks * 16);

  // ones A-fragment (bf16 1.0) for the lsum MFMA
  short8 onesf;
#pragma unroll
  for (int e = 0; e < 8; ++e) onesf[e] = (short)0x3F80;

  // ---- staging geometry: 16 gload_lds per tile (4/wave), 1KB contiguous each ----
  int lrow = l >> 3;                                     // 0..7 (row&7 within instr)
  int j0 = w * 2;                                        // this wave's 2 K + 2 V instrs
  int g0B = (((l & 7) ^ lrow ^ j0) << 4);                // source chunk bytes, instr j0
  int g1B = (((l & 7) ^ lrow ^ (j0 + 1)) << 4);          // source chunk bytes, instr j0+1
  size_t kg0 = (size_t)(8 * j0 + lrow) * 128 + g0B;      // + kv0*128
  size_t kg1 = (size_t)(8 * j0 + 8 + lrow) * 128 + g1B;
  size_t vg0 = (size_t)(8 * j0 + lrow) * 4096 + g0B;     // + kv0*2
  size_t vg1 = (size_t)(8 * j0 + 8 + lrow) * 4096 + g1B;

  // ---- fragment read offsets (ushort idx), loop-invariant ----
  int koff0[4], koff1[4];
#pragma unroll
  for (int ks = 0; ks < 4; ++ks) {
    int srow = (lo & 7) ^ (lo >> 3);
    koff0[ks] = lo * 64 + (((2 * ks + hi) ^ srow) << 3);
    koff1[ks] = (lo + 32) * 64 + (((2 * ks + hi) ^ srow ^ 4) << 3);
  }

#define STAGE_KV(Kd, Vd, kvoff) do {                                  \
    GLOAD_LDS16(KbB + (size_t)(kvoff) * 128 + kg0, (Kd) + j0 * 512);  \
    GLOAD_LDS16(KbB + (size_t)(kvoff) * 128 + kg1, (Kd) + (j0 + 1) * 512); \
    GLOAD_LDS16(VbB + (size_t)(kvoff) * 2 + vg0, (Vd) + j0 * 512);    \
    GLOAD_LDS16(VbB + (size_t)(kvoff) * 2 + vg1, (Vd) + (j0 + 1) * 512); \
  } while (0)

  // rotating buffer pointers: read Kc/Vc, stage 3-ahead into K3/V3
  unsigned short *Kc = &Kls[0][0], *K1 = &Kls[1][0], *K2 = &Kls[2][0], *K3 = &Kls[3][0];
  unsigned short *Vc = &Vls[0][0], *V1 = &Vls[1][0], *V2 = &Vls[2][0], *V3 = &Vls[3][0];

  // ---- prologue: stage tiles 0,1,2 (12 loads/wave in flight) ----
  STAGE_KV(Kc, Vc, 0);
  STAGE_KV(K1, V1, 64);
  STAGE_KV(K2, V2, 128);

  const f32x16 zf = {0.f,0.f,0.f,0.f,0.f,0.f,0.f,0.f,0.f,0.f,0.f,0.f,0.f,0.f,0.f,0.f};
  f32x16 ot0 = zf, ot1 = zf;
  f32x16 lacc = zf;               // lsum accumulator: only lacc[0] is ever read
  float m = -1e30f;

  for (int it = 0; it < 32; ++it) {
    // wait ONLY for the tile staged 3 iters ago (8 newer loads stay in flight)
    asm volatile("s_waitcnt vmcnt(8)" ::: "memory");
    __builtin_amdgcn_s_barrier();
    // stage tile it+3 into the buffer last read at iter it-1 (wrap: harmless re-stage)
    STAGE_KV(K3, V3, ((it + 3) & 31) * 64);

    // ---- K fragments from LDS (conflict-free swizzled b128 reads) ----
    short8 kf0[4], kf1[4];
#pragma unroll
    for (int ks = 0; ks < 4; ++ks) {
      kf0[ks] = *(const short8*)&Kc[koff0[ks]];
      kf1[ks] = *(const short8*)&Kc[koff1[ks]];
    }
    f32x16 st0 = zf, st1 = zf;
    __builtin_amdgcn_s_setprio(1);
#pragma unroll
    for (int ks = 0; ks < 4; ++ks) {
      st0 = MFMA32(kf0[ks], qf[ks], st0);
      st1 = MFMA32(kf1[ks], qf[ks], st1);
    }
    __builtin_amdgcn_s_setprio(0);
    // ---- V fragments (time-share regs with kf; overlap reads with softmax) ----
    short8 vf0[4], vf1[4];
#pragma unroll
    for (int ks = 0; ks < 4; ++ks) {
      vf0[ks] = *(const short8*)&Vc[koff0[ks]];
      vf1[ks] = *(const short8*)&Vc[koff1[ks]];
    }

    // ---- in-register online softmax (log2 domain); max via v_max3_f32 tree ----
    float a0 = max3f(st0[0], st0[1], st0[2]);
    float a1 = max3f(st0[3], st0[4], st0[5]);
    float a2 = max3f(st0[6], st0[7], st0[8]);
    float a3 = max3f(st0[9], st0[10], st0[11]);
    float a4 = max3f(st0[12], st0[13], st0[14]);
    float b0 = max3f(st1[0], st1[1], st1[2]);
    float b1 = max3f(st1[3], st1[4], st1[5]);
    float b2 = max3f(st1[6], st1[7], st1[8]);
    float b3 = max3f(st1[9], st1[10], st1[11]);
    float b4 = max3f(st1[12], st1[13], st1[14]);
    float c0 = max3f(a0, a1, a2);
    float c1 = max3f(a3, a4, st0[15]);
    float c2 = max3f(b0, b1, b2);
    float c3 = max3f(b3, b4, st1[15]);
    float pmaxh = fmaxf(max3f(c0, c1, c2), c3);
    // cross-half combine via permlane32_swap (VALU, no LDS)
    uint2v msw = __builtin_amdgcn_permlane32_swap(__builtin_bit_cast(unsigned, pmaxh),
                                                  __builtin_bit_cast(unsigned, pmaxh),
                                                  false, false);
    float pmax = fmaxf(__builtin_bit_cast(float, msw[0]), __builtin_bit_cast(float, msw[1]));
    // defer-max: only rescale when running max grew by > 8 (log2) => P bounded by 2^8
    if (!__all(pmax - m <= 8.0f)) {
      float mnew = fmaxf(m, pmax);
      float alpha = exp2f(m - mnew);
      m = mnew;
      lacc[0] *= alpha;
#pragma unroll
      for (int r = 0; r < 16; ++r) { ot0[r] *= alpha; ot1[r] *= alpha; }
    }

    // ---- two-phase P = exp2(S - m), pack to PV B-operand (no VALU sum needed) ----
    short8 pb[4];
    float p[16];
    // phase A: st0 -> pb[0], pb[1]
#pragma unroll
    for (int r = 0; r < 16; ++r) p[r] = exp2f(st0[r] - m);
    {
      unsigned x0 = cvtpk(p[0], p[1]),  x1 = cvtpk(p[2], p[3]);
      unsigned y0 = cvtpk(p[4], p[5]),  y1 = cvtpk(p[6], p[7]);
      uint2v sw0 = __builtin_amdgcn_permlane32_swap(x0, y0, false, false);
      uint2v sw1 = __builtin_amdgcn_permlane32_swap(x1, y1, false, false);
      uint4v pk; pk[0] = sw0[0]; pk[1] = sw1[0]; pk[2] = sw0[1]; pk[3] = sw1[1];
      pb[0] = __builtin_bit_cast(short8, pk);
      unsigned x2 = cvtpk(p[8], p[9]),  x3 = cvtpk(p[10], p[11]);
      unsigned y2 = cvtpk(p[12], p[13]), y3 = cvtpk(p[14], p[15]);
      uint2v sw2 = __builtin_amdgcn_permlane32_swap(x2, y2, false, false);
      uint2v sw3 = __builtin_amdgcn_permlane32_swap(x3, y3, false, false);
      uint4v pk1; pk1[0] = sw2[0]; pk1[1] = sw3[0]; pk1[2] = sw2[1]; pk1[3] = sw3[1];
      pb[1] = __builtin_bit_cast(short8, pk1);
    }
    // phase B: st1 -> pb[2], pb[3] (reuses p[] registers)
#pragma unroll
    for (int r = 0; r < 16; ++r) p[r] = exp2f(st1[r] - m);
    {
      unsigned x0 = cvtpk(p[0], p[1]),  x1 = cvtpk(p[2], p[3]);
      unsigned y0 = cvtpk(p[4], p[5]),  y1 = cvtpk(p[6], p[7]);
      uint2v sw0 = __builtin_amdgcn_permlane32_swap(x0, y0, false, false);
      uint2v sw1 = __builtin_amdgcn_permlane32_swap(x1, y1, false, false);
      uint4v pk; pk[0] = sw0[0]; pk[1] = sw1[0]; pk[2] = sw0[1]; pk[3] = sw1[1];
      pb[2] = __builtin_bit_cast(short8, pk);
      unsigned x2 = cvtpk(p[8], p[9]),  x3 = cvtpk(p[10], p[11]);
      unsigned y2 = cvtpk(p[12], p[13]), y3 = cvtpk(p[14], p[15]);
      uint2v sw2 = __builtin_amdgcn_permlane32_swap(x2, y2, false, false);
      uint2v sw3 = __builtin_amdgcn_permlane32_swap(x3, y3, false, false);
      uint4v pk1; pk1[0] = sw2[0]; pk1[1] = sw3[0]; pk1[2] = sw2[1]; pk1[3] = sw3[1];
      pb[3] = __builtin_bit_cast(short8, pk1);
    }

    // ---- PV + lsum (ones-row) on the matrix pipe ----
    __builtin_amdgcn_s_setprio(1);
#pragma unroll
    for (int ks = 0; ks < 4; ++ks) {
      ot0 = MFMA32(vf0[ks], pb[ks], ot0);
      ot1 = MFMA32(vf1[ks], pb[ks], ot1);
      lacc = MFMA32(onesf, pb[ks], lacc);   // D[i][q] = sum_k P[k][q] (all rows equal)
    }
    __builtin_amdgcn_s_setprio(0);

    // rotate buffers: (cur,1,2,3) -> (1,2,3,cur)
    unsigned short* tk = Kc; Kc = K1; K1 = K2; K2 = K3; K3 = tk;
    unsigned short* tv = Vc; Vc = V1; V1 = V2; V2 = V3; V3 = tv;
  }

  // ---- finalize: inv = 1/lacc[0] (full-k sum, per-lane q), store bf16 ----
  float inv = 1.0f / lacc[0];
  int b = bh >> 4, h = bh & 15;
  unsigned short* orow = attn_out + ((size_t)(b * 2048 + qi)) * 1024 + h * 64 + 4 * hi;
#pragma unroll
  for (int g = 0; g < 4; ++g) {
    uint2v u0, u1;
    u0[0] = cvtpk(ot0[4*g + 0] * inv, ot0[4*g + 1] * inv);
    u0[1] = cvtpk(ot0[4*g + 2] * inv, ot0[4*g + 3] * inv);
    u1[0] = cvtpk(ot1[4*g + 0] * inv, ot1[4*g + 1] * inv);
    u1[1] = cvtpk(ot1[4*g + 2] * inv, ot1[4*g + 3] * inv);
    *(uint2v*)(orow + 8 * g) = u0;         // d = 8g+4hi+0..3
    *(uint2v*)(orow + 32 + 8 * g) = u1;    // d = 32+8g+4hi+0..3
  }
}

extern "C" void kernel_launch(void* const* d_in, const int* in_sizes, int n_in,
                              void* d_out, int out_size, void* d_ws, size_t ws_size,
                              hipStream_t stream) {
  (void)in_sizes; (void)n_in; (void)out_size; (void)ws_size;
  const float* x     = (const float*)d_in[0];
  const float* W_qkv = (const float*)d_in[1];
  const float* b_qkv = (const float*)d_in[2];
  const float* W_out = (const float*)d_in[3];
  const float* b_out = (const float*)d_in[4];
  float* out = (float*)d_out;
  char* ws = (char*)d_ws;
  unsigned short* xb    = (unsigned short*)(ws);             // 8192x1024 bf16
  unsigned short* WqkvT = (unsigned short*)(ws + 16777216);  // 3072x1024 bf16
  unsigned short* WoutT = (unsigned short*)(ws + 23068672);  // 1024x1024 bf16
  unsigned short* Qb    = (unsigned short*)(ws + 25165824);  // 64x2048x64 bf16
  unsigned short* Kb    = (unsigned short*)(ws + 41943040);  // 64x2048x64 bf16
  unsigned short* Vb    = (unsigned short*)(ws + 58720256);  // 64x2048x64 bf16
  unsigned short* Vtb   = (unsigned short*)(ws + 75497472);  // 64x64x2048 bf16
  unsigned short* attnb = (unsigned short*)(ws + 92274688);  // 8192x1024 bf16

  cvt_f32_bf16<<<8192, 256, 0, stream>>>(x, xb);
  cvt_transpose<<<dim3(16, 48), 256, 0, stream>>>(W_qkv, WqkvT, 1024, 3072);
  cvt_transpose<<<dim3(16, 16), 256, 0, stream>>>(W_out, WoutT, 1024, 1024);
  gemm_qkv<<<dim3(64, 24), 256, 0, stream>>>(xb, WqkvT, b_qkv, Qb, Kb, Vb);
  transpose_v<<<dim3(64, 32), 256, 0, stream>>>(Vb, Vtb);
  attn_fwd2<<<1024, 256, 0, stream>>>(Qb, Kb, Vtb, attnb);
  gemm_out<<<dim3(64, 8), 256, 0, stream>>>(attnb, WoutT, b_out, out);
}